// Round 12
// baseline (437.563 us; speedup 1.0000x reference)
//
#include <hip/hip_runtime.h>
#include <hip/hip_bf16.h>

// GIN: 2 x (CSR gather-sum + MLP(64->64->64) + BatchNorm + ReLU) + mean pool
// N=50000 nodes, E=800000 edges, H=64, G=16 graphs. fp32 in/out.
// R12: dispatch-count reduction (R11: ~9us/dispatch replay overhead x 14).
// scan1+scan3 -> one single-block scan; layer-0 norm fused into layer-1 agg
// (mlp dual-writes raw fp32+bf16, aggn normalizes on gather, stats ping-pong);
// pool finalize folded into pool via completion counter. 14 -> 11 dispatches.

constexpr int NN = 50000;
constexpr int NE = 800000;
constexpr int HD = 64;
constexpr int NG = 16;
constexpr float BN_EPS = 1e-5f;
constexpr int NBUCK = (NN + 1023) / 1024;        // 49 coarse buckets (dst>>10)
constexpr int BIN1_BLOCKS = (NE + 4095) / 4096;  // 196

// ---------------------------------------------------------------------------
// fp32 -> bf16 table conversion; also zeroes cnt[] for count_kernel.
// ---------------------------------------------------------------------------
__global__ __launch_bounds__(256)
void x2bf_kernel(const float* __restrict__ x, __hip_bfloat16* __restrict__ xb,
                 int* __restrict__ cnt) {
    int i4 = blockIdx.x * 256 + threadIdx.x;
    if (i4 < NN) cnt[i4] = 0;
    if (i4 >= NN * HD / 4) return;
    float4 v = *(const float4*)(x + (size_t)i4 * 4);
    union { ushort4 u; __hip_bfloat16 b[4]; } p;
    p.b[0] = __float2bfloat16(v.x);
    p.b[1] = __float2bfloat16(v.y);
    p.b[2] = __float2bfloat16(v.z);
    p.b[3] = __float2bfloat16(v.w);
    *(ushort4*)((unsigned short*)xb + (size_t)i4 * 4) = p.u;
}

// ---------------------------------------------------------------------------
// Degree histogram (4 edges/thread, int4 dst loads).
// ---------------------------------------------------------------------------
__global__ __launch_bounds__(256)
void count_kernel(const int* __restrict__ ei, int* __restrict__ cnt) {
    int e4 = (blockIdx.x * 256 + threadIdx.x) * 4;
    if (e4 >= NE) return;
    int4 d = *(const int4*)(ei + NE + e4);
    atomicAdd(&cnt[d.x], 1);
    atomicAdd(&cnt[d.y], 1);
    atomicAdd(&cnt[d.z], 1);
    atomicAdd(&cnt[d.w], 1);
}

// ---------------------------------------------------------------------------
// Single-block exclusive scan of cnt -> row_ptr; seeds coarse-bucket cursors.
// 1024 threads x 49 contiguous elements each; LDS scan of thread totals.
// ---------------------------------------------------------------------------
__global__ __launch_bounds__(1024)
void scan_kernel(const int* __restrict__ cnt, int* __restrict__ row_ptr,
                 int* __restrict__ gcur) {
    __shared__ int sums[1024];
    int t = threadIdx.x;
    const int C = 49;  // 1024*49 = 50176 >= NN
    int base = t * C;
    int s = 0;
    for (int i = 0; i < C; i++) {
        int idx = base + i;
        s += (idx < NN) ? cnt[idx] : 0;
    }
    sums[t] = s;
    __syncthreads();
    for (int off = 1; off < 1024; off <<= 1) {
        int add = (t >= off) ? sums[t - off] : 0;
        __syncthreads();
        sums[t] += add;
        __syncthreads();
    }
    int run = sums[t] - s;  // exclusive base for this thread's range
    for (int i = 0; i < C; i++) {
        int idx = base + i;
        if (idx < NN) {
            int c = cnt[idx];
            row_ptr[idx] = run;
            if ((idx & 1023) == 0) gcur[idx >> 10] = run;
            run += c;
        }
    }
    if (t == 1023) row_ptr[NN] = NE;
}

// ---------------------------------------------------------------------------
// Pass 1: LDS-binned partition into 49 coarse dst-buckets (chunk-claim
// atomics only; pair writes contiguous per (block,bucket) chunk).
// ---------------------------------------------------------------------------
__global__ __launch_bounds__(256)
void bin1_kernel(const int* __restrict__ ei, int* __restrict__ gcur,
                 int2* __restrict__ part) {
    __shared__ int lcnt[NBUCK];
    __shared__ int lbase[NBUCK];
    __shared__ int lcur[NBUCK];
    int tid = threadIdx.x;
    int chunk = blockIdx.x * 4096;
    if (tid < NBUCK) lcnt[tid] = 0;
    __syncthreads();
#pragma unroll
    for (int r = 0; r < 16; r++) {
        int e = chunk + r * 256 + tid;
        if (e < NE) atomicAdd(&lcnt[ei[NE + e] >> 10], 1);
    }
    __syncthreads();
    if (tid < NBUCK) {
        lbase[tid] = atomicAdd(&gcur[tid], lcnt[tid]);
        lcur[tid] = 0;
    }
    __syncthreads();
#pragma unroll
    for (int r = 0; r < 16; r++) {
        int e = chunk + r * 256 + tid;
        if (e < NE) {
            int src = ei[e];
            int dst = ei[NE + e];
            int b = dst >> 10;
            int slot = atomicAdd(&lcur[b], 1);
            part[lbase[b] + slot] = make_int2(src, dst);
        }
    }
}

// ---------------------------------------------------------------------------
// Pass 2: one block per coarse bucket; LDS row cursors; csr writes confined
// to this bucket's contiguous window.
// ---------------------------------------------------------------------------
__global__ __launch_bounds__(256)
void bin2_kernel(const int2* __restrict__ part, const int* __restrict__ row_ptr,
                 int* __restrict__ csr) {
    __shared__ int lcur[1024];
    int b = blockIdx.x;
    int base_row = b << 10;
    for (int i = threadIdx.x; i < 1024; i += 256)
        lcur[i] = row_ptr[min(base_row + i, NN)];
    __syncthreads();
    int s = row_ptr[min(base_row, NN)];
    int e = row_ptr[min(base_row + 1024, NN)];
    for (int i = s + threadIdx.x; i < e; i += 256) {
        int2 p = part[i];
        int pos = atomicAdd(&lcur[p.y & 1023], 1);
        csr[pos] = p.x;
    }
}

// ---------------------------------------------------------------------------
// Layer-0 aggregation: one wave per dst row, 8-deep gather pipeline.
// h[r] = x_f32[r] + sum_nb bf16(x)[nb]. Block 0 zeroes stats0.
// ---------------------------------------------------------------------------
__global__ __launch_bounds__(256)
void agg_kernel(const float* __restrict__ x, const __hip_bfloat16* __restrict__ xb,
                const int* __restrict__ row_ptr, const int* __restrict__ csr,
                float* __restrict__ h, float* __restrict__ stats) {
    if (blockIdx.x == 0 && threadIdx.x < 128) stats[threadIdx.x] = 0.f;
    int row = blockIdx.x * 4 + (threadIdx.x >> 6);
    int lane = threadIdx.x & 63;
    int s = row_ptr[row], e = row_ptr[row + 1];
    int cnt = e - s;
    int ids = (lane < cnt) ? csr[s + lane] : 0;
    float acc = x[(size_t)row * HD + lane];
    int m = min(cnt, 64);
    int j = 0;
    float a0 = 0.f, a1 = 0.f, a2 = 0.f, a3 = 0.f;
    float a4 = 0.f, a5 = 0.f, a6 = 0.f, a7 = 0.f;
    for (; j + 8 <= m; j += 8) {
        int nb0 = __shfl(ids, j);
        int nb1 = __shfl(ids, j + 1);
        int nb2 = __shfl(ids, j + 2);
        int nb3 = __shfl(ids, j + 3);
        int nb4 = __shfl(ids, j + 4);
        int nb5 = __shfl(ids, j + 5);
        int nb6 = __shfl(ids, j + 6);
        int nb7 = __shfl(ids, j + 7);
        a0 += __bfloat162float(xb[(size_t)nb0 * HD + lane]);
        a1 += __bfloat162float(xb[(size_t)nb1 * HD + lane]);
        a2 += __bfloat162float(xb[(size_t)nb2 * HD + lane]);
        a3 += __bfloat162float(xb[(size_t)nb3 * HD + lane]);
        a4 += __bfloat162float(xb[(size_t)nb4 * HD + lane]);
        a5 += __bfloat162float(xb[(size_t)nb5 * HD + lane]);
        a6 += __bfloat162float(xb[(size_t)nb6 * HD + lane]);
        a7 += __bfloat162float(xb[(size_t)nb7 * HD + lane]);
    }
    acc += ((a0 + a1) + (a2 + a3)) + ((a4 + a5) + (a6 + a7));
    for (; j < m; j++) {
        int nb = __shfl(ids, j);
        acc += __bfloat162float(xb[(size_t)nb * HD + lane]);
    }
    for (int jj = s + 64; jj < e; jj++) {
        acc += __bfloat162float(xb[(size_t)csr[jj] * HD + lane]);
    }
    h[(size_t)row * HD + lane] = acc;
}

// ---------------------------------------------------------------------------
// Layer-1 aggregation with fused BatchNorm+ReLU of the previous layer:
// y(v) = max(v*sc + off, 0) applied to the fp32 self-term (hraw) and every
// gathered bf16 raw neighbor. sc/off derived from stats_prev (layer-0 stats).
// Block 0 zeroes stats_next.
// ---------------------------------------------------------------------------
__global__ __launch_bounds__(256)
void aggn_kernel(const float* __restrict__ hraw, const __hip_bfloat16* __restrict__ xbr,
                 const int* __restrict__ row_ptr, const int* __restrict__ csr,
                 const float* __restrict__ stats_prev, const float* __restrict__ g0,
                 const float* __restrict__ be0,
                 float* __restrict__ h, float* __restrict__ stats_next) {
    if (blockIdx.x == 0 && threadIdx.x < 128) stats_next[threadIdx.x] = 0.f;
    int row = blockIdx.x * 4 + (threadIdx.x >> 6);
    int lane = threadIdx.x & 63;
    const float inv = 1.f / (float)NN;
    float mu = stats_prev[lane] * inv;
    float var = stats_prev[64 + lane] * inv - mu * mu;
    float sc = g0[lane] * rsqrtf(var + BN_EPS);
    float off = be0[lane] - mu * sc;
    int s = row_ptr[row], e = row_ptr[row + 1];
    int cnt = e - s;
    int ids = (lane < cnt) ? csr[s + lane] : 0;
    float acc = fmaxf(fmaf(hraw[(size_t)row * HD + lane], sc, off), 0.f);
    int m = min(cnt, 64);
    int j = 0;
    float a0 = 0.f, a1 = 0.f, a2 = 0.f, a3 = 0.f;
    float a4 = 0.f, a5 = 0.f, a6 = 0.f, a7 = 0.f;
    for (; j + 8 <= m; j += 8) {
        int nb0 = __shfl(ids, j);
        int nb1 = __shfl(ids, j + 1);
        int nb2 = __shfl(ids, j + 2);
        int nb3 = __shfl(ids, j + 3);
        int nb4 = __shfl(ids, j + 4);
        int nb5 = __shfl(ids, j + 5);
        int nb6 = __shfl(ids, j + 6);
        int nb7 = __shfl(ids, j + 7);
        float v0 = __bfloat162float(xbr[(size_t)nb0 * HD + lane]);
        float v1 = __bfloat162float(xbr[(size_t)nb1 * HD + lane]);
        float v2 = __bfloat162float(xbr[(size_t)nb2 * HD + lane]);
        float v3 = __bfloat162float(xbr[(size_t)nb3 * HD + lane]);
        float v4 = __bfloat162float(xbr[(size_t)nb4 * HD + lane]);
        float v5 = __bfloat162float(xbr[(size_t)nb5 * HD + lane]);
        float v6 = __bfloat162float(xbr[(size_t)nb6 * HD + lane]);
        float v7 = __bfloat162float(xbr[(size_t)nb7 * HD + lane]);
        a0 += fmaxf(fmaf(v0, sc, off), 0.f);
        a1 += fmaxf(fmaf(v1, sc, off), 0.f);
        a2 += fmaxf(fmaf(v2, sc, off), 0.f);
        a3 += fmaxf(fmaf(v3, sc, off), 0.f);
        a4 += fmaxf(fmaf(v4, sc, off), 0.f);
        a5 += fmaxf(fmaf(v5, sc, off), 0.f);
        a6 += fmaxf(fmaf(v6, sc, off), 0.f);
        a7 += fmaxf(fmaf(v7, sc, off), 0.f);
    }
    acc += ((a0 + a1) + (a2 + a3)) + ((a4 + a5) + (a6 + a7));
    for (; j < m; j++) {
        int nb = __shfl(ids, j);
        float v = __bfloat162float(xbr[(size_t)nb * HD + lane]);
        acc += fmaxf(fmaf(v, sc, off), 0.f);
    }
    for (int jj = s + 64; jj < e; jj++) {
        float v = __bfloat162float(xbr[(size_t)csr[jj] * HD + lane]);
        acc += fmaxf(fmaf(v, sc, off), 0.f);
    }
    h[(size_t)row * HD + lane] = acc;
}

// ---------------------------------------------------------------------------
// Fused MLP + BN-stats epilogue. hout = ReLU(hin @ W1 + b1) @ W2 + b2 (raw).
// Optional dual-write of bf16 raw output (xbr != nullptr) for the next
// layer's normalize-on-gather. Block 0 zeroes psums + pool counter.
// ---------------------------------------------------------------------------
__global__ __launch_bounds__(256)
void mlp_kernel(const float* __restrict__ hin, float* __restrict__ hout,
                const float* __restrict__ W1, const float* __restrict__ b1,
                const float* __restrict__ W2, const float* __restrict__ b2,
                float* __restrict__ stats, float* __restrict__ psums,
                int* __restrict__ pctr, __hip_bfloat16* __restrict__ xbr) {
    __shared__ float sh[128 * 65];
    __shared__ float sW[64 * 64];
    __shared__ float sb[64];
    __shared__ float red[2][4][64];
    int tid = threadIdx.x;
    int base = blockIdx.x * 128;

    if (blockIdx.x == 0) {
        float4 z = make_float4(0.f, 0.f, 0.f, 0.f);
        *(float4*)(psums + tid * 4) = z;
        if (tid == 0) pctr[0] = 0;
    }
    for (int i = tid; i < 4096; i += 256) sW[i] = W1[i];
    if (tid < 64) sb[tid] = b1[tid];
#pragma unroll
    for (int i = 0; i < 8; i++) {
        int i4 = tid + 256 * i;
        int row = i4 >> 4, col = (i4 & 15) * 4;
        int grow = base + row;
        float4 v = (grow < NN) ? *(const float4*)(hin + (size_t)grow * HD + col)
                               : make_float4(0.f, 0.f, 0.f, 0.f);
        float* d = sh + row * 65 + col;
        d[0] = v.x; d[1] = v.y; d[2] = v.z; d[3] = v.w;
    }
    __syncthreads();

    int wv = tid >> 6;
    int lane = tid & 63;

    float acc0[16], acc1[16];
    // ---- GEMM1 ----
#pragma unroll
    for (int j = 0; j < 16; j++) { acc0[j] = sb[wv * 16 + j]; acc1[j] = acc0[j]; }
    for (int k = 0; k < 64; k++) {
        float a0 = sh[lane * 65 + k];
        float a1 = sh[(64 + lane) * 65 + k];
        const float4* wr = (const float4*)(sW + k * 64 + wv * 16);
#pragma unroll
        for (int q = 0; q < 4; q++) {
            float4 w = wr[q];
            acc0[4 * q + 0] = fmaf(a0, w.x, acc0[4 * q + 0]);
            acc0[4 * q + 1] = fmaf(a0, w.y, acc0[4 * q + 1]);
            acc0[4 * q + 2] = fmaf(a0, w.z, acc0[4 * q + 2]);
            acc0[4 * q + 3] = fmaf(a0, w.w, acc0[4 * q + 3]);
            acc1[4 * q + 0] = fmaf(a1, w.x, acc1[4 * q + 0]);
            acc1[4 * q + 1] = fmaf(a1, w.y, acc1[4 * q + 1]);
            acc1[4 * q + 2] = fmaf(a1, w.z, acc1[4 * q + 2]);
            acc1[4 * q + 3] = fmaf(a1, w.w, acc1[4 * q + 3]);
        }
    }
    __syncthreads();

    // t = ReLU(acc) overwrites sh; restage W2/b2
#pragma unroll
    for (int j = 0; j < 16; j++) {
        sh[lane * 65 + wv * 16 + j] = fmaxf(acc0[j], 0.f);
        sh[(64 + lane) * 65 + wv * 16 + j] = fmaxf(acc1[j], 0.f);
    }
    for (int i = tid; i < 4096; i += 256) sW[i] = W2[i];
    if (tid < 64) sb[tid] = b2[tid];
    __syncthreads();

    // ---- GEMM2 ----
#pragma unroll
    for (int j = 0; j < 16; j++) { acc0[j] = sb[wv * 16 + j]; acc1[j] = acc0[j]; }
    for (int k = 0; k < 64; k++) {
        float a0 = sh[lane * 65 + k];
        float a1 = sh[(64 + lane) * 65 + k];
        const float4* wr = (const float4*)(sW + k * 64 + wv * 16);
#pragma unroll
        for (int q = 0; q < 4; q++) {
            float4 w = wr[q];
            acc0[4 * q + 0] = fmaf(a0, w.x, acc0[4 * q + 0]);
            acc0[4 * q + 1] = fmaf(a0, w.y, acc0[4 * q + 1]);
            acc0[4 * q + 2] = fmaf(a0, w.z, acc0[4 * q + 2]);
            acc0[4 * q + 3] = fmaf(a0, w.w, acc0[4 * q + 3]);
            acc1[4 * q + 0] = fmaf(a1, w.x, acc1[4 * q + 0]);
            acc1[4 * q + 1] = fmaf(a1, w.y, acc1[4 * q + 1]);
            acc1[4 * q + 2] = fmaf(a1, w.z, acc1[4 * q + 2]);
            acc1[4 * q + 3] = fmaf(a1, w.w, acc1[4 * q + 3]);
        }
    }
    __syncthreads();
#pragma unroll
    for (int j = 0; j < 16; j++) {
        sh[lane * 65 + wv * 16 + j] = acc0[j];
        sh[(64 + lane) * 65 + wv * 16 + j] = acc1[j];
    }
    __syncthreads();

    // coalesced stores: fp32 always; bf16 raw table if requested
#pragma unroll
    for (int i = 0; i < 8; i++) {
        int i4 = tid + 256 * i;
        int row = i4 >> 4, col = (i4 & 15) * 4;
        int grow = base + row;
        if (grow < NN) {
            const float* s = sh + row * 65 + col;
            float4 v = make_float4(s[0], s[1], s[2], s[3]);
            *(float4*)(hout + (size_t)grow * HD + col) = v;
            if (xbr) {
                union { ushort4 u; __hip_bfloat16 b[4]; } p;
                p.b[0] = __float2bfloat16(v.x);
                p.b[1] = __float2bfloat16(v.y);
                p.b[2] = __float2bfloat16(v.z);
                p.b[3] = __float2bfloat16(v.w);
                *(ushort4*)((unsigned short*)xbr + (size_t)grow * HD + col) = p.u;
            }
        }
    }

    // ---- fused BN-stats partials ----
    {
        int col = tid & 63;
        int r0 = (tid >> 6) * 32;
        float s = 0.f, ss = 0.f;
#pragma unroll
        for (int r = 0; r < 32; r++) {
            float v = (base + r0 + r < NN) ? sh[(r0 + r) * 65 + col] : 0.f;
            s += v;
            ss += v * v;
        }
        red[0][tid >> 6][col] = s;
        red[1][tid >> 6][col] = ss;
        __syncthreads();
        if (tid < 64) {
            float S = red[0][0][col] + red[0][1][col] + red[0][2][col] + red[0][3][col];
            atomicAdd(stats + col, S);
        } else if (tid < 128) {
            float SS = red[1][0][col] + red[1][1][col] + red[1][2][col] + red[1][3][col];
            atomicAdd(stats + 64 + col, SS);
        }
    }
}

// ---------------------------------------------------------------------------
// Final BatchNorm + affine + ReLU, in-place on out (no bf16 dual-write).
// ---------------------------------------------------------------------------
__global__ __launch_bounds__(256)
void norm_kernel(float* h, const float* __restrict__ stats,
                 const float* __restrict__ g, const float* __restrict__ be) {
    size_t i4 = (size_t)blockIdx.x * 256 + threadIdx.x;
    if (i4 >= (size_t)NN * HD / 4) return;
    size_t off = i4 * 4;
    int col = (int)(off & 63);
    float4 v = *(const float4*)(h + off);
    float4 sm = *(const float4*)(stats + col);
    float4 sq = *(const float4*)(stats + 64 + col);
    float4 gg = *(const float4*)(g + col);
    float4 bb = *(const float4*)(be + col);
    const float inv = 1.f / (float)NN;
    float4 o;
    {
        float mu = sm.x * inv, var = sq.x * inv - mu * mu;
        float sc = gg.x * rsqrtf(var + BN_EPS);
        o.x = fmaxf((v.x - mu) * sc + bb.x, 0.f);
    }
    {
        float mu = sm.y * inv, var = sq.y * inv - mu * mu;
        float sc = gg.y * rsqrtf(var + BN_EPS);
        o.y = fmaxf((v.y - mu) * sc + bb.y, 0.f);
    }
    {
        float mu = sm.z * inv, var = sq.z * inv - mu * mu;
        float sc = gg.z * rsqrtf(var + BN_EPS);
        o.z = fmaxf((v.z - mu) * sc + bb.z, 0.f);
    }
    {
        float mu = sm.w * inv, var = sq.w * inv - mu * mu;
        float sc = gg.w * rsqrtf(var + BN_EPS);
        o.w = fmaxf((v.w - mu) * sc + bb.w, 0.f);
    }
    *(float4*)(h + off) = o;
}

// ---------------------------------------------------------------------------
// Mean pool, single dispatch: 200 partial blocks; last-arriving block (via
// completion counter) finalizes. psums re-read with atomicAdd(p,0) so the
// reads are L2-coherent with the producers' atomics.
// ---------------------------------------------------------------------------
__device__ __forceinline__ int lower_bound_batch(const int* __restrict__ b, int val) {
    int lo = 0, hi = NN;
    while (lo < hi) {
        int mid = (lo + hi) >> 1;
        if (b[mid] < val) lo = mid + 1;
        else hi = mid;
    }
    return lo;
}

__global__ __launch_bounds__(256)
void pool_kernel(const float* __restrict__ x, const int* __restrict__ batch,
                 float* __restrict__ sums, int* __restrict__ pctr,
                 float* __restrict__ out) {
    int col = threadIdx.x & 63;
    int rl = threadIdx.x >> 6;
    int rs = blockIdx.x * 250;
    int re = rs + 250;
    int cur = -1;
    float acc = 0.f;
    for (int r = rs + rl; r < re; r += 4) {
        int g = batch[r];
        float v = x[(size_t)r * HD + col];
        if (g != cur) {
            if (cur >= 0) atomicAdd(&sums[cur * HD + col], acc);
            cur = g;
            acc = v;
        } else {
            acc += v;
        }
    }
    if (cur >= 0) atomicAdd(&sums[cur * HD + col], acc);

    __threadfence();
    __shared__ int last;
    if (threadIdx.x == 0) last = (atomicAdd(pctr, 1) == gridDim.x - 1);
    __syncthreads();
    if (!last) return;
    __threadfence();
    for (int i = threadIdx.x; i < NG * HD; i += 256) {
        int g = i >> 6;
        float sum = atomicAdd(&sums[i], 0.0f);  // coherent read-through
        int s = lower_bound_batch(batch, g);
        int e = lower_bound_batch(batch, g + 1);
        out[i] = sum / fmaxf((float)(e - s), 1.f);
    }
}

extern "C" void kernel_launch(void* const* d_in, const int* in_sizes, int n_in,
                              void* d_out, int out_size, void* d_ws, size_t ws_size,
                              hipStream_t stream) {
    const float* x = (const float*)d_in[0];
    const int* ei = (const int*)d_in[1];
    const int* batch = (const int*)d_in[2];
    const float* W1_0 = (const float*)d_in[3];
    const float* b1_0 = (const float*)d_in[4];
    const float* W2_0 = (const float*)d_in[5];
    const float* b2_0 = (const float*)d_in[6];
    const float* g_0 = (const float*)d_in[7];
    const float* be_0 = (const float*)d_in[8];
    const float* W1_1 = (const float*)d_in[9];
    const float* b1_1 = (const float*)d_in[10];
    const float* W2_1 = (const float*)d_in[11];
    const float* b2_1 = (const float*)d_in[12];
    const float* g_1 = (const float*)d_in[13];
    const float* be_1 = (const float*)d_in[14];

    float* out = (float*)d_out;  // raw L0 h2 -> raw L1 h2 -> final normalized

    // workspace layout (~30 MB)
    float* buf_h = (float*)d_ws;                       // NN*HD f32
    float* stats0 = buf_h + (size_t)NN * HD;           // 128 f32
    float* stats1 = stats0 + 128;                      // 128 f32
    float* psums = stats1 + 128;                       // 1024 f32
    int* pctr = (int*)(psums + 1024);                  // 64 ints (1 used)
    int* row_ptr = pctr + 64;                          // NN+2
    int* cnt = row_ptr + (NN + 2);                     // NN
    int* gcur = cnt + NN;                              // 64
    int* csr = gcur + 64;                              // NE
    __hip_bfloat16* xb = (__hip_bfloat16*)(csr + NE);  // NN*HD bf16 (reused for raw table)
    int2* part = (int2*)(xb + (size_t)NN * HD);        // NE int2

    dim3 b256(256);
    int mlp_grid = (NN + 127) / 128;              // 391
    int norm_grid = (NN * HD / 4 + 255) / 256;    // 3125
    int cnt_grid = (NE / 4 + 255) / 256;          // 782
    int agg_grid = NN / 4;                        // 12500

    // ---- CSR build ----
    x2bf_kernel<<<norm_grid, b256, 0, stream>>>(x, xb, cnt);
    count_kernel<<<cnt_grid, b256, 0, stream>>>(ei, cnt);
    scan_kernel<<<1, dim3(1024), 0, stream>>>(cnt, row_ptr, gcur);
    bin1_kernel<<<BIN1_BLOCKS, b256, 0, stream>>>(ei, gcur, part);
    bin2_kernel<<<NBUCK, b256, 0, stream>>>(part, row_ptr, csr);

    // ---- layer 0 ----
    agg_kernel<<<agg_grid, b256, 0, stream>>>(x, xb, row_ptr, csr, buf_h, stats0);
    mlp_kernel<<<mlp_grid, b256, 0, stream>>>(buf_h, out, W1_0, b1_0, W2_0, b2_0,
                                              stats0, psums, pctr, xb);

    // ---- layer 1 (agg applies layer-0 BN+ReLU on the fly) ----
    aggn_kernel<<<agg_grid, b256, 0, stream>>>(out, xb, row_ptr, csr,
                                               stats0, g_0, be_0, buf_h, stats1);
    mlp_kernel<<<mlp_grid, b256, 0, stream>>>(buf_h, out, W1_1, b1_1, W2_1, b2_1,
                                              stats1, psums, pctr, (__hip_bfloat16*)nullptr);
    norm_kernel<<<norm_grid, b256, 0, stream>>>(out, stats1, g_1, be_1);

    // ---- pool (single dispatch) ----
    pool_kernel<<<200, b256, 0, stream>>>(out, batch, psums, pctr, out + (size_t)NN * HD);
}

// Round 13
// 352.846 us; speedup vs baseline: 1.2401x; 1.2401x over previous
//
#include <hip/hip_runtime.h>
#include <hip/hip_bf16.h>

// GIN: 2 x (CSR gather-sum + MLP(64->64->64) + BatchNorm + ReLU) + mean pool
// N=50000 nodes, E=800000 edges, H=64, G=16 graphs. fp32 in/out.
// R13: reverted R12's single-block scan (93us: 1 CU, latency-serialized -- a
// 9us dispatch saving never pays for an +84us serial kernel). Back to R11's
// 196-block scan1 + scan3 pair. Kept: aggn fusion (L0 norm on gather), fused
// single-dispatch pool, int4 count, mlp bf16 dual-write. 12 dispatches.

constexpr int NN = 50000;
constexpr int NE = 800000;
constexpr int HD = 64;
constexpr int NG = 16;
constexpr float BN_EPS = 1e-5f;
constexpr int SCAN_BLOCKS = (NN + 255) / 256;    // 196
constexpr int NBUCK = (NN + 1023) / 1024;        // 49 coarse buckets (dst>>10)
constexpr int BIN1_BLOCKS = (NE + 4095) / 4096;  // 196

// ---------------------------------------------------------------------------
// fp32 -> bf16 table conversion; also zeroes cnt[] for count_kernel.
// ---------------------------------------------------------------------------
__global__ __launch_bounds__(256)
void x2bf_kernel(const float* __restrict__ x, __hip_bfloat16* __restrict__ xb,
                 int* __restrict__ cnt) {
    int i4 = blockIdx.x * 256 + threadIdx.x;
    if (i4 < NN) cnt[i4] = 0;
    if (i4 >= NN * HD / 4) return;
    float4 v = *(const float4*)(x + (size_t)i4 * 4);
    union { ushort4 u; __hip_bfloat16 b[4]; } p;
    p.b[0] = __float2bfloat16(v.x);
    p.b[1] = __float2bfloat16(v.y);
    p.b[2] = __float2bfloat16(v.z);
    p.b[3] = __float2bfloat16(v.w);
    *(ushort4*)((unsigned short*)xb + (size_t)i4 * 4) = p.u;
}

// ---------------------------------------------------------------------------
// Degree histogram (4 edges/thread, int4 dst loads).
// ---------------------------------------------------------------------------
__global__ __launch_bounds__(256)
void count_kernel(const int* __restrict__ ei, int* __restrict__ cnt) {
    int e4 = (blockIdx.x * 256 + threadIdx.x) * 4;
    if (e4 >= NE) return;
    int4 d = *(const int4*)(ei + NE + e4);
    atomicAdd(&cnt[d.x], 1);
    atomicAdd(&cnt[d.y], 1);
    atomicAdd(&cnt[d.z], 1);
    atomicAdd(&cnt[d.w], 1);
}

// ---------------------------------------------------------------------------
// Parallel scan (R11 form): per-256-chunk scan + finalize that redundantly
// prefix-sums the 196 partials per block. Seeds coarse-bucket cursors.
// ---------------------------------------------------------------------------
__global__ __launch_bounds__(256)
void scan1_kernel(const int* __restrict__ cnt, int* __restrict__ row_ptr,
                  int* __restrict__ partials) {
    int i = blockIdx.x * 256 + threadIdx.x;
    int v = (i < NN) ? cnt[i] : 0;
    __shared__ int s[256];
    s[threadIdx.x] = v;
    __syncthreads();
#pragma unroll
    for (int off = 1; off < 256; off <<= 1) {
        int add = (threadIdx.x >= off) ? s[threadIdx.x - off] : 0;
        __syncthreads();
        s[threadIdx.x] += add;
        __syncthreads();
    }
    if (i < NN) row_ptr[i] = s[threadIdx.x] - v;  // exclusive
    if (threadIdx.x == 255) partials[blockIdx.x] = s[255];
}

__global__ __launch_bounds__(256)
void scan3_kernel(int* __restrict__ row_ptr, const int* __restrict__ partials,
                  int* __restrict__ gcur) {
    __shared__ int s[256];
    __shared__ int orig[256];
    int v = (threadIdx.x < SCAN_BLOCKS) ? partials[threadIdx.x] : 0;
    s[threadIdx.x] = v;
    orig[threadIdx.x] = v;
    __syncthreads();
#pragma unroll
    for (int off = 1; off < 256; off <<= 1) {
        int add = (threadIdx.x >= off) ? s[threadIdx.x - off] : 0;
        __syncthreads();
        s[threadIdx.x] += add;
        __syncthreads();
    }
    int poff = s[blockIdx.x] - orig[blockIdx.x];  // exclusive block offset
    int i = blockIdx.x * 256 + threadIdx.x;
    if (i < NN) {
        int rv = row_ptr[i] + poff;
        row_ptr[i] = rv;
        if ((i & 1023) == 0) gcur[i >> 10] = rv;  // coarse bucket base
    }
    if (i == 0) row_ptr[NN] = NE;
}

// ---------------------------------------------------------------------------
// Pass 1: LDS-binned partition into 49 coarse dst-buckets (chunk-claim
// atomics only; pair writes contiguous per (block,bucket) chunk).
// ---------------------------------------------------------------------------
__global__ __launch_bounds__(256)
void bin1_kernel(const int* __restrict__ ei, int* __restrict__ gcur,
                 int2* __restrict__ part) {
    __shared__ int lcnt[NBUCK];
    __shared__ int lbase[NBUCK];
    __shared__ int lcur[NBUCK];
    int tid = threadIdx.x;
    int chunk = blockIdx.x * 4096;
    if (tid < NBUCK) lcnt[tid] = 0;
    __syncthreads();
#pragma unroll
    for (int r = 0; r < 16; r++) {
        int e = chunk + r * 256 + tid;
        if (e < NE) atomicAdd(&lcnt[ei[NE + e] >> 10], 1);
    }
    __syncthreads();
    if (tid < NBUCK) {
        lbase[tid] = atomicAdd(&gcur[tid], lcnt[tid]);
        lcur[tid] = 0;
    }
    __syncthreads();
#pragma unroll
    for (int r = 0; r < 16; r++) {
        int e = chunk + r * 256 + tid;
        if (e < NE) {
            int src = ei[e];
            int dst = ei[NE + e];
            int b = dst >> 10;
            int slot = atomicAdd(&lcur[b], 1);
            part[lbase[b] + slot] = make_int2(src, dst);
        }
    }
}

// ---------------------------------------------------------------------------
// Pass 2: one block per coarse bucket; LDS row cursors; csr writes confined
// to this bucket's contiguous window.
// ---------------------------------------------------------------------------
__global__ __launch_bounds__(256)
void bin2_kernel(const int2* __restrict__ part, const int* __restrict__ row_ptr,
                 int* __restrict__ csr) {
    __shared__ int lcur[1024];
    int b = blockIdx.x;
    int base_row = b << 10;
    for (int i = threadIdx.x; i < 1024; i += 256)
        lcur[i] = row_ptr[min(base_row + i, NN)];
    __syncthreads();
    int s = row_ptr[min(base_row, NN)];
    int e = row_ptr[min(base_row + 1024, NN)];
    for (int i = s + threadIdx.x; i < e; i += 256) {
        int2 p = part[i];
        int pos = atomicAdd(&lcur[p.y & 1023], 1);
        csr[pos] = p.x;
    }
}

// ---------------------------------------------------------------------------
// Layer-0 aggregation: one wave per dst row, 8-deep gather pipeline.
// h[r] = x_f32[r] + sum_nb bf16(x)[nb]. Block 0 zeroes stats0.
// ---------------------------------------------------------------------------
__global__ __launch_bounds__(256)
void agg_kernel(const float* __restrict__ x, const __hip_bfloat16* __restrict__ xb,
                const int* __restrict__ row_ptr, const int* __restrict__ csr,
                float* __restrict__ h, float* __restrict__ stats) {
    if (blockIdx.x == 0 && threadIdx.x < 128) stats[threadIdx.x] = 0.f;
    int row = blockIdx.x * 4 + (threadIdx.x >> 6);
    int lane = threadIdx.x & 63;
    int s = row_ptr[row], e = row_ptr[row + 1];
    int cnt = e - s;
    int ids = (lane < cnt) ? csr[s + lane] : 0;
    float acc = x[(size_t)row * HD + lane];
    int m = min(cnt, 64);
    int j = 0;
    float a0 = 0.f, a1 = 0.f, a2 = 0.f, a3 = 0.f;
    float a4 = 0.f, a5 = 0.f, a6 = 0.f, a7 = 0.f;
    for (; j + 8 <= m; j += 8) {
        int nb0 = __shfl(ids, j);
        int nb1 = __shfl(ids, j + 1);
        int nb2 = __shfl(ids, j + 2);
        int nb3 = __shfl(ids, j + 3);
        int nb4 = __shfl(ids, j + 4);
        int nb5 = __shfl(ids, j + 5);
        int nb6 = __shfl(ids, j + 6);
        int nb7 = __shfl(ids, j + 7);
        a0 += __bfloat162float(xb[(size_t)nb0 * HD + lane]);
        a1 += __bfloat162float(xb[(size_t)nb1 * HD + lane]);
        a2 += __bfloat162float(xb[(size_t)nb2 * HD + lane]);
        a3 += __bfloat162float(xb[(size_t)nb3 * HD + lane]);
        a4 += __bfloat162float(xb[(size_t)nb4 * HD + lane]);
        a5 += __bfloat162float(xb[(size_t)nb5 * HD + lane]);
        a6 += __bfloat162float(xb[(size_t)nb6 * HD + lane]);
        a7 += __bfloat162float(xb[(size_t)nb7 * HD + lane]);
    }
    acc += ((a0 + a1) + (a2 + a3)) + ((a4 + a5) + (a6 + a7));
    for (; j < m; j++) {
        int nb = __shfl(ids, j);
        acc += __bfloat162float(xb[(size_t)nb * HD + lane]);
    }
    for (int jj = s + 64; jj < e; jj++) {
        acc += __bfloat162float(xb[(size_t)csr[jj] * HD + lane]);
    }
    h[(size_t)row * HD + lane] = acc;
}

// ---------------------------------------------------------------------------
// Layer-1 aggregation with fused BatchNorm+ReLU of the previous layer:
// y(v) = max(v*sc + off, 0) on the fp32 self-term and every gathered bf16 raw
// neighbor. sc/off from stats_prev. Block 0 zeroes stats_next.
// ---------------------------------------------------------------------------
__global__ __launch_bounds__(256)
void aggn_kernel(const float* __restrict__ hraw, const __hip_bfloat16* __restrict__ xbr,
                 const int* __restrict__ row_ptr, const int* __restrict__ csr,
                 const float* __restrict__ stats_prev, const float* __restrict__ g0,
                 const float* __restrict__ be0,
                 float* __restrict__ h, float* __restrict__ stats_next) {
    if (blockIdx.x == 0 && threadIdx.x < 128) stats_next[threadIdx.x] = 0.f;
    int row = blockIdx.x * 4 + (threadIdx.x >> 6);
    int lane = threadIdx.x & 63;
    const float inv = 1.f / (float)NN;
    float mu = stats_prev[lane] * inv;
    float var = stats_prev[64 + lane] * inv - mu * mu;
    float sc = g0[lane] * rsqrtf(var + BN_EPS);
    float off = be0[lane] - mu * sc;
    int s = row_ptr[row], e = row_ptr[row + 1];
    int cnt = e - s;
    int ids = (lane < cnt) ? csr[s + lane] : 0;
    float acc = fmaxf(fmaf(hraw[(size_t)row * HD + lane], sc, off), 0.f);
    int m = min(cnt, 64);
    int j = 0;
    float a0 = 0.f, a1 = 0.f, a2 = 0.f, a3 = 0.f;
    float a4 = 0.f, a5 = 0.f, a6 = 0.f, a7 = 0.f;
    for (; j + 8 <= m; j += 8) {
        int nb0 = __shfl(ids, j);
        int nb1 = __shfl(ids, j + 1);
        int nb2 = __shfl(ids, j + 2);
        int nb3 = __shfl(ids, j + 3);
        int nb4 = __shfl(ids, j + 4);
        int nb5 = __shfl(ids, j + 5);
        int nb6 = __shfl(ids, j + 6);
        int nb7 = __shfl(ids, j + 7);
        float v0 = __bfloat162float(xbr[(size_t)nb0 * HD + lane]);
        float v1 = __bfloat162float(xbr[(size_t)nb1 * HD + lane]);
        float v2 = __bfloat162float(xbr[(size_t)nb2 * HD + lane]);
        float v3 = __bfloat162float(xbr[(size_t)nb3 * HD + lane]);
        float v4 = __bfloat162float(xbr[(size_t)nb4 * HD + lane]);
        float v5 = __bfloat162float(xbr[(size_t)nb5 * HD + lane]);
        float v6 = __bfloat162float(xbr[(size_t)nb6 * HD + lane]);
        float v7 = __bfloat162float(xbr[(size_t)nb7 * HD + lane]);
        a0 += fmaxf(fmaf(v0, sc, off), 0.f);
        a1 += fmaxf(fmaf(v1, sc, off), 0.f);
        a2 += fmaxf(fmaf(v2, sc, off), 0.f);
        a3 += fmaxf(fmaf(v3, sc, off), 0.f);
        a4 += fmaxf(fmaf(v4, sc, off), 0.f);
        a5 += fmaxf(fmaf(v5, sc, off), 0.f);
        a6 += fmaxf(fmaf(v6, sc, off), 0.f);
        a7 += fmaxf(fmaf(v7, sc, off), 0.f);
    }
    acc += ((a0 + a1) + (a2 + a3)) + ((a4 + a5) + (a6 + a7));
    for (; j < m; j++) {
        int nb = __shfl(ids, j);
        float v = __bfloat162float(xbr[(size_t)nb * HD + lane]);
        acc += fmaxf(fmaf(v, sc, off), 0.f);
    }
    for (int jj = s + 64; jj < e; jj++) {
        float v = __bfloat162float(xbr[(size_t)csr[jj] * HD + lane]);
        acc += fmaxf(fmaf(v, sc, off), 0.f);
    }
    h[(size_t)row * HD + lane] = acc;
}

// ---------------------------------------------------------------------------
// Fused MLP + BN-stats epilogue. hout = ReLU(hin @ W1 + b1) @ W2 + b2 (raw).
// Optional bf16 raw dual-write for the next layer's normalize-on-gather.
// Block 0 zeroes psums + pool counter.
// ---------------------------------------------------------------------------
__global__ __launch_bounds__(256)
void mlp_kernel(const float* __restrict__ hin, float* __restrict__ hout,
                const float* __restrict__ W1, const float* __restrict__ b1,
                const float* __restrict__ W2, const float* __restrict__ b2,
                float* __restrict__ stats, float* __restrict__ psums,
                int* __restrict__ pctr, __hip_bfloat16* __restrict__ xbr) {
    __shared__ float sh[128 * 65];
    __shared__ float sW[64 * 64];
    __shared__ float sb[64];
    __shared__ float red[2][4][64];
    int tid = threadIdx.x;
    int base = blockIdx.x * 128;

    if (blockIdx.x == 0) {
        float4 z = make_float4(0.f, 0.f, 0.f, 0.f);
        *(float4*)(psums + tid * 4) = z;
        if (tid == 0) pctr[0] = 0;
    }
    for (int i = tid; i < 4096; i += 256) sW[i] = W1[i];
    if (tid < 64) sb[tid] = b1[tid];
#pragma unroll
    for (int i = 0; i < 8; i++) {
        int i4 = tid + 256 * i;
        int row = i4 >> 4, col = (i4 & 15) * 4;
        int grow = base + row;
        float4 v = (grow < NN) ? *(const float4*)(hin + (size_t)grow * HD + col)
                               : make_float4(0.f, 0.f, 0.f, 0.f);
        float* d = sh + row * 65 + col;
        d[0] = v.x; d[1] = v.y; d[2] = v.z; d[3] = v.w;
    }
    __syncthreads();

    int wv = tid >> 6;
    int lane = tid & 63;

    float acc0[16], acc1[16];
    // ---- GEMM1 ----
#pragma unroll
    for (int j = 0; j < 16; j++) { acc0[j] = sb[wv * 16 + j]; acc1[j] = acc0[j]; }
    for (int k = 0; k < 64; k++) {
        float a0 = sh[lane * 65 + k];
        float a1 = sh[(64 + lane) * 65 + k];
        const float4* wr = (const float4*)(sW + k * 64 + wv * 16);
#pragma unroll
        for (int q = 0; q < 4; q++) {
            float4 w = wr[q];
            acc0[4 * q + 0] = fmaf(a0, w.x, acc0[4 * q + 0]);
            acc0[4 * q + 1] = fmaf(a0, w.y, acc0[4 * q + 1]);
            acc0[4 * q + 2] = fmaf(a0, w.z, acc0[4 * q + 2]);
            acc0[4 * q + 3] = fmaf(a0, w.w, acc0[4 * q + 3]);
            acc1[4 * q + 0] = fmaf(a1, w.x, acc1[4 * q + 0]);
            acc1[4 * q + 1] = fmaf(a1, w.y, acc1[4 * q + 1]);
            acc1[4 * q + 2] = fmaf(a1, w.z, acc1[4 * q + 2]);
            acc1[4 * q + 3] = fmaf(a1, w.w, acc1[4 * q + 3]);
        }
    }
    __syncthreads();

    // t = ReLU(acc) overwrites sh; restage W2/b2
#pragma unroll
    for (int j = 0; j < 16; j++) {
        sh[lane * 65 + wv * 16 + j] = fmaxf(acc0[j], 0.f);
        sh[(64 + lane) * 65 + wv * 16 + j] = fmaxf(acc1[j], 0.f);
    }
    for (int i = tid; i < 4096; i += 256) sW[i] = W2[i];
    if (tid < 64) sb[tid] = b2[tid];
    __syncthreads();

    // ---- GEMM2 ----
#pragma unroll
    for (int j = 0; j < 16; j++) { acc0[j] = sb[wv * 16 + j]; acc1[j] = acc0[j]; }
    for (int k = 0; k < 64; k++) {
        float a0 = sh[lane * 65 + k];
        float a1 = sh[(64 + lane) * 65 + k];
        const float4* wr = (const float4*)(sW + k * 64 + wv * 16);
#pragma unroll
        for (int q = 0; q < 4; q++) {
            float4 w = wr[q];
            acc0[4 * q + 0] = fmaf(a0, w.x, acc0[4 * q + 0]);
            acc0[4 * q + 1] = fmaf(a0, w.y, acc0[4 * q + 1]);
            acc0[4 * q + 2] = fmaf(a0, w.z, acc0[4 * q + 2]);
            acc0[4 * q + 3] = fmaf(a0, w.w, acc0[4 * q + 3]);
            acc1[4 * q + 0] = fmaf(a1, w.x, acc1[4 * q + 0]);
            acc1[4 * q + 1] = fmaf(a1, w.y, acc1[4 * q + 1]);
            acc1[4 * q + 2] = fmaf(a1, w.z, acc1[4 * q + 2]);
            acc1[4 * q + 3] = fmaf(a1, w.w, acc1[4 * q + 3]);
        }
    }
    __syncthreads();
#pragma unroll
    for (int j = 0; j < 16; j++) {
        sh[lane * 65 + wv * 16 + j] = acc0[j];
        sh[(64 + lane) * 65 + wv * 16 + j] = acc1[j];
    }
    __syncthreads();

    // coalesced stores: fp32 always; bf16 raw table if requested
#pragma unroll
    for (int i = 0; i < 8; i++) {
        int i4 = tid + 256 * i;
        int row = i4 >> 4, col = (i4 & 15) * 4;
        int grow = base + row;
        if (grow < NN) {
            const float* s = sh + row * 65 + col;
            float4 v = make_float4(s[0], s[1], s[2], s[3]);
            *(float4*)(hout + (size_t)grow * HD + col) = v;
            if (xbr) {
                union { ushort4 u; __hip_bfloat16 b[4]; } p;
                p.b[0] = __float2bfloat16(v.x);
                p.b[1] = __float2bfloat16(v.y);
                p.b[2] = __float2bfloat16(v.z);
                p.b[3] = __float2bfloat16(v.w);
                *(ushort4*)((unsigned short*)xbr + (size_t)grow * HD + col) = p.u;
            }
        }
    }

    // ---- fused BN-stats partials ----
    {
        int col = tid & 63;
        int r0 = (tid >> 6) * 32;
        float s = 0.f, ss = 0.f;
#pragma unroll
        for (int r = 0; r < 32; r++) {
            float v = (base + r0 + r < NN) ? sh[(r0 + r) * 65 + col] : 0.f;
            s += v;
            ss += v * v;
        }
        red[0][tid >> 6][col] = s;
        red[1][tid >> 6][col] = ss;
        __syncthreads();
        if (tid < 64) {
            float S = red[0][0][col] + red[0][1][col] + red[0][2][col] + red[0][3][col];
            atomicAdd(stats + col, S);
        } else if (tid < 128) {
            float SS = red[1][0][col] + red[1][1][col] + red[1][2][col] + red[1][3][col];
            atomicAdd(stats + 64 + col, SS);
        }
    }
}

// ---------------------------------------------------------------------------
// Final BatchNorm + affine + ReLU, in-place on out.
// ---------------------------------------------------------------------------
__global__ __launch_bounds__(256)
void norm_kernel(float* h, const float* __restrict__ stats,
                 const float* __restrict__ g, const float* __restrict__ be) {
    size_t i4 = (size_t)blockIdx.x * 256 + threadIdx.x;
    if (i4 >= (size_t)NN * HD / 4) return;
    size_t off = i4 * 4;
    int col = (int)(off & 63);
    float4 v = *(const float4*)(h + off);
    float4 sm = *(const float4*)(stats + col);
    float4 sq = *(const float4*)(stats + 64 + col);
    float4 gg = *(const float4*)(g + col);
    float4 bb = *(const float4*)(be + col);
    const float inv = 1.f / (float)NN;
    float4 o;
    {
        float mu = sm.x * inv, var = sq.x * inv - mu * mu;
        float sc = gg.x * rsqrtf(var + BN_EPS);
        o.x = fmaxf((v.x - mu) * sc + bb.x, 0.f);
    }
    {
        float mu = sm.y * inv, var = sq.y * inv - mu * mu;
        float sc = gg.y * rsqrtf(var + BN_EPS);
        o.y = fmaxf((v.y - mu) * sc + bb.y, 0.f);
    }
    {
        float mu = sm.z * inv, var = sq.z * inv - mu * mu;
        float sc = gg.z * rsqrtf(var + BN_EPS);
        o.z = fmaxf((v.z - mu) * sc + bb.z, 0.f);
    }
    {
        float mu = sm.w * inv, var = sq.w * inv - mu * mu;
        float sc = gg.w * rsqrtf(var + BN_EPS);
        o.w = fmaxf((v.w - mu) * sc + bb.w, 0.f);
    }
    *(float4*)(h + off) = o;
}

// ---------------------------------------------------------------------------
// Mean pool, single dispatch: 200 partial blocks; last block finalizes.
// ---------------------------------------------------------------------------
__device__ __forceinline__ int lower_bound_batch(const int* __restrict__ b, int val) {
    int lo = 0, hi = NN;
    while (lo < hi) {
        int mid = (lo + hi) >> 1;
        if (b[mid] < val) lo = mid + 1;
        else hi = mid;
    }
    return lo;
}

__global__ __launch_bounds__(256)
void pool_kernel(const float* __restrict__ x, const int* __restrict__ batch,
                 float* __restrict__ sums, int* __restrict__ pctr,
                 float* __restrict__ out) {
    int col = threadIdx.x & 63;
    int rl = threadIdx.x >> 6;
    int rs = blockIdx.x * 250;
    int re = rs + 250;
    int cur = -1;
    float acc = 0.f;
    for (int r = rs + rl; r < re; r += 4) {
        int g = batch[r];
        float v = x[(size_t)r * HD + col];
        if (g != cur) {
            if (cur >= 0) atomicAdd(&sums[cur * HD + col], acc);
            cur = g;
            acc = v;
        } else {
            acc += v;
        }
    }
    if (cur >= 0) atomicAdd(&sums[cur * HD + col], acc);

    __threadfence();
    __shared__ int last;
    if (threadIdx.x == 0) last = (atomicAdd(pctr, 1) == gridDim.x - 1);
    __syncthreads();
    if (!last) return;
    __threadfence();
    for (int i = threadIdx.x; i < NG * HD; i += 256) {
        int g = i >> 6;
        float sum = atomicAdd(&sums[i], 0.0f);  // coherent read-through
        int s = lower_bound_batch(batch, g);
        int e = lower_bound_batch(batch, g + 1);
        out[i] = sum / fmaxf((float)(e - s), 1.f);
    }
}

extern "C" void kernel_launch(void* const* d_in, const int* in_sizes, int n_in,
                              void* d_out, int out_size, void* d_ws, size_t ws_size,
                              hipStream_t stream) {
    const float* x = (const float*)d_in[0];
    const int* ei = (const int*)d_in[1];
    const int* batch = (const int*)d_in[2];
    const float* W1_0 = (const float*)d_in[3];
    const float* b1_0 = (const float*)d_in[4];
    const float* W2_0 = (const float*)d_in[5];
    const float* b2_0 = (const float*)d_in[6];
    const float* g_0 = (const float*)d_in[7];
    const float* be_0 = (const float*)d_in[8];
    const float* W1_1 = (const float*)d_in[9];
    const float* b1_1 = (const float*)d_in[10];
    const float* W2_1 = (const float*)d_in[11];
    const float* b2_1 = (const float*)d_in[12];
    const float* g_1 = (const float*)d_in[13];
    const float* be_1 = (const float*)d_in[14];

    float* out = (float*)d_out;  // raw L0 h2 -> raw L1 h2 -> final normalized

    // workspace layout (~30 MB)
    float* buf_h = (float*)d_ws;                       // NN*HD f32
    float* stats0 = buf_h + (size_t)NN * HD;           // 128 f32
    float* stats1 = stats0 + 128;                      // 128 f32
    float* psums = stats1 + 128;                       // 1024 f32
    int* pctr = (int*)(psums + 1024);                  // 64 ints (1 used)
    int* row_ptr = pctr + 64;                          // NN+2
    int* cnt = row_ptr + (NN + 2);                     // NN
    int* partials = cnt + NN;                          // 256
    int* gcur = partials + 256;                        // 64
    int* csr = gcur + 64;                              // NE
    __hip_bfloat16* xb = (__hip_bfloat16*)(csr + NE);  // NN*HD bf16
    int2* part = (int2*)(xb + (size_t)NN * HD);        // NE int2

    dim3 b256(256);
    int mlp_grid = (NN + 127) / 128;              // 391
    int norm_grid = (NN * HD / 4 + 255) / 256;    // 3125
    int cnt_grid = (NE / 4 + 255) / 256;          // 782
    int agg_grid = NN / 4;                        // 12500

    // ---- CSR build ----
    x2bf_kernel<<<norm_grid, b256, 0, stream>>>(x, xb, cnt);
    count_kernel<<<cnt_grid, b256, 0, stream>>>(ei, cnt);
    scan1_kernel<<<SCAN_BLOCKS, b256, 0, stream>>>(cnt, row_ptr, partials);
    scan3_kernel<<<SCAN_BLOCKS, b256, 0, stream>>>(row_ptr, partials, gcur);
    bin1_kernel<<<BIN1_BLOCKS, b256, 0, stream>>>(ei, gcur, part);
    bin2_kernel<<<NBUCK, b256, 0, stream>>>(part, row_ptr, csr);

    // ---- layer 0 ----
    agg_kernel<<<agg_grid, b256, 0, stream>>>(x, xb, row_ptr, csr, buf_h, stats0);
    mlp_kernel<<<mlp_grid, b256, 0, stream>>>(buf_h, out, W1_0, b1_0, W2_0, b2_0,
                                              stats0, psums, pctr, xb);

    // ---- layer 1 (agg applies layer-0 BN+ReLU on the fly) ----
    aggn_kernel<<<agg_grid, b256, 0, stream>>>(out, xb, row_ptr, csr,
                                               stats0, g_0, be_0, buf_h, stats1);
    mlp_kernel<<<mlp_grid, b256, 0, stream>>>(buf_h, out, W1_1, b1_1, W2_1, b2_1,
                                              stats1, psums, pctr, (__hip_bfloat16*)nullptr);
    norm_kernel<<<norm_grid, b256, 0, stream>>>(out, stats1, g_1, be_1);

    // ---- pool (single dispatch) ----
    pool_kernel<<<200, b256, 0, stream>>>(out, batch, psums, pctr, out + (size_t)NN * HD);
}

// Round 14
// 322.196 us; speedup vs baseline: 1.3581x; 1.0951x over previous
//
#include <hip/hip_runtime.h>
#include <hip/hip_bf16.h>

// GIN: 2 x (CSR gather-sum + MLP(64->64->64) + BatchNorm + ReLU) + mean pool
// N=50000 nodes, E=800000 edges, H=64, G=16 graphs. fp32 in/out.
// R14: killed R13's 58us fused pool (200 blocks x __threadfence = L2 drain
// per block; 117 GB/s). Pool partials now fused into norm_kernel via LDS
// reduction + fire-and-forget atomics (mlp-stats pattern, NOT R9's serialized
// RMW claims); tiny finalize dispatch for the division. 12 dispatches.

constexpr int NN = 50000;
constexpr int NE = 800000;
constexpr int HD = 64;
constexpr int NG = 16;
constexpr float BN_EPS = 1e-5f;
constexpr int SCAN_BLOCKS = (NN + 255) / 256;    // 196
constexpr int NBUCK = (NN + 1023) / 1024;        // 49 coarse buckets (dst>>10)
constexpr int BIN1_BLOCKS = (NE + 4095) / 4096;  // 196

// ---------------------------------------------------------------------------
// fp32 -> bf16 table conversion; also zeroes cnt[] for count_kernel.
// ---------------------------------------------------------------------------
__global__ __launch_bounds__(256)
void x2bf_kernel(const float* __restrict__ x, __hip_bfloat16* __restrict__ xb,
                 int* __restrict__ cnt) {
    int i4 = blockIdx.x * 256 + threadIdx.x;
    if (i4 < NN) cnt[i4] = 0;
    if (i4 >= NN * HD / 4) return;
    float4 v = *(const float4*)(x + (size_t)i4 * 4);
    union { ushort4 u; __hip_bfloat16 b[4]; } p;
    p.b[0] = __float2bfloat16(v.x);
    p.b[1] = __float2bfloat16(v.y);
    p.b[2] = __float2bfloat16(v.z);
    p.b[3] = __float2bfloat16(v.w);
    *(ushort4*)((unsigned short*)xb + (size_t)i4 * 4) = p.u;
}

// ---------------------------------------------------------------------------
// Degree histogram (4 edges/thread, int4 dst loads).
// ---------------------------------------------------------------------------
__global__ __launch_bounds__(256)
void count_kernel(const int* __restrict__ ei, int* __restrict__ cnt) {
    int e4 = (blockIdx.x * 256 + threadIdx.x) * 4;
    if (e4 >= NE) return;
    int4 d = *(const int4*)(ei + NE + e4);
    atomicAdd(&cnt[d.x], 1);
    atomicAdd(&cnt[d.y], 1);
    atomicAdd(&cnt[d.z], 1);
    atomicAdd(&cnt[d.w], 1);
}

// ---------------------------------------------------------------------------
// Parallel scan: per-256-chunk scan + finalize (redundant partials-scan per
// block). Seeds coarse-bucket cursors.
// ---------------------------------------------------------------------------
__global__ __launch_bounds__(256)
void scan1_kernel(const int* __restrict__ cnt, int* __restrict__ row_ptr,
                  int* __restrict__ partials) {
    int i = blockIdx.x * 256 + threadIdx.x;
    int v = (i < NN) ? cnt[i] : 0;
    __shared__ int s[256];
    s[threadIdx.x] = v;
    __syncthreads();
#pragma unroll
    for (int off = 1; off < 256; off <<= 1) {
        int add = (threadIdx.x >= off) ? s[threadIdx.x - off] : 0;
        __syncthreads();
        s[threadIdx.x] += add;
        __syncthreads();
    }
    if (i < NN) row_ptr[i] = s[threadIdx.x] - v;  // exclusive
    if (threadIdx.x == 255) partials[blockIdx.x] = s[255];
}

__global__ __launch_bounds__(256)
void scan3_kernel(int* __restrict__ row_ptr, const int* __restrict__ partials,
                  int* __restrict__ gcur) {
    __shared__ int s[256];
    __shared__ int orig[256];
    int v = (threadIdx.x < SCAN_BLOCKS) ? partials[threadIdx.x] : 0;
    s[threadIdx.x] = v;
    orig[threadIdx.x] = v;
    __syncthreads();
#pragma unroll
    for (int off = 1; off < 256; off <<= 1) {
        int add = (threadIdx.x >= off) ? s[threadIdx.x - off] : 0;
        __syncthreads();
        s[threadIdx.x] += add;
        __syncthreads();
    }
    int poff = s[blockIdx.x] - orig[blockIdx.x];  // exclusive block offset
    int i = blockIdx.x * 256 + threadIdx.x;
    if (i < NN) {
        int rv = row_ptr[i] + poff;
        row_ptr[i] = rv;
        if ((i & 1023) == 0) gcur[i >> 10] = rv;  // coarse bucket base
    }
    if (i == 0) row_ptr[NN] = NE;
}

// ---------------------------------------------------------------------------
// Pass 1: LDS-binned partition into 49 coarse dst-buckets.
// ---------------------------------------------------------------------------
__global__ __launch_bounds__(256)
void bin1_kernel(const int* __restrict__ ei, int* __restrict__ gcur,
                 int2* __restrict__ part) {
    __shared__ int lcnt[NBUCK];
    __shared__ int lbase[NBUCK];
    __shared__ int lcur[NBUCK];
    int tid = threadIdx.x;
    int chunk = blockIdx.x * 4096;
    if (tid < NBUCK) lcnt[tid] = 0;
    __syncthreads();
#pragma unroll
    for (int r = 0; r < 16; r++) {
        int e = chunk + r * 256 + tid;
        if (e < NE) atomicAdd(&lcnt[ei[NE + e] >> 10], 1);
    }
    __syncthreads();
    if (tid < NBUCK) {
        lbase[tid] = atomicAdd(&gcur[tid], lcnt[tid]);
        lcur[tid] = 0;
    }
    __syncthreads();
#pragma unroll
    for (int r = 0; r < 16; r++) {
        int e = chunk + r * 256 + tid;
        if (e < NE) {
            int src = ei[e];
            int dst = ei[NE + e];
            int b = dst >> 10;
            int slot = atomicAdd(&lcur[b], 1);
            part[lbase[b] + slot] = make_int2(src, dst);
        }
    }
}

// ---------------------------------------------------------------------------
// Pass 2: one block per coarse bucket; LDS row cursors; block-local csr
// window writes.
// ---------------------------------------------------------------------------
__global__ __launch_bounds__(256)
void bin2_kernel(const int2* __restrict__ part, const int* __restrict__ row_ptr,
                 int* __restrict__ csr) {
    __shared__ int lcur[1024];
    int b = blockIdx.x;
    int base_row = b << 10;
    for (int i = threadIdx.x; i < 1024; i += 256)
        lcur[i] = row_ptr[min(base_row + i, NN)];
    __syncthreads();
    int s = row_ptr[min(base_row, NN)];
    int e = row_ptr[min(base_row + 1024, NN)];
    for (int i = s + threadIdx.x; i < e; i += 256) {
        int2 p = part[i];
        int pos = atomicAdd(&lcur[p.y & 1023], 1);
        csr[pos] = p.x;
    }
}

// ---------------------------------------------------------------------------
// Layer-0 aggregation: one wave per dst row, 8-deep gather pipeline.
// ---------------------------------------------------------------------------
__global__ __launch_bounds__(256)
void agg_kernel(const float* __restrict__ x, const __hip_bfloat16* __restrict__ xb,
                const int* __restrict__ row_ptr, const int* __restrict__ csr,
                float* __restrict__ h, float* __restrict__ stats) {
    if (blockIdx.x == 0 && threadIdx.x < 128) stats[threadIdx.x] = 0.f;
    int row = blockIdx.x * 4 + (threadIdx.x >> 6);
    int lane = threadIdx.x & 63;
    int s = row_ptr[row], e = row_ptr[row + 1];
    int cnt = e - s;
    int ids = (lane < cnt) ? csr[s + lane] : 0;
    float acc = x[(size_t)row * HD + lane];
    int m = min(cnt, 64);
    int j = 0;
    float a0 = 0.f, a1 = 0.f, a2 = 0.f, a3 = 0.f;
    float a4 = 0.f, a5 = 0.f, a6 = 0.f, a7 = 0.f;
    for (; j + 8 <= m; j += 8) {
        int nb0 = __shfl(ids, j);
        int nb1 = __shfl(ids, j + 1);
        int nb2 = __shfl(ids, j + 2);
        int nb3 = __shfl(ids, j + 3);
        int nb4 = __shfl(ids, j + 4);
        int nb5 = __shfl(ids, j + 5);
        int nb6 = __shfl(ids, j + 6);
        int nb7 = __shfl(ids, j + 7);
        a0 += __bfloat162float(xb[(size_t)nb0 * HD + lane]);
        a1 += __bfloat162float(xb[(size_t)nb1 * HD + lane]);
        a2 += __bfloat162float(xb[(size_t)nb2 * HD + lane]);
        a3 += __bfloat162float(xb[(size_t)nb3 * HD + lane]);
        a4 += __bfloat162float(xb[(size_t)nb4 * HD + lane]);
        a5 += __bfloat162float(xb[(size_t)nb5 * HD + lane]);
        a6 += __bfloat162float(xb[(size_t)nb6 * HD + lane]);
        a7 += __bfloat162float(xb[(size_t)nb7 * HD + lane]);
    }
    acc += ((a0 + a1) + (a2 + a3)) + ((a4 + a5) + (a6 + a7));
    for (; j < m; j++) {
        int nb = __shfl(ids, j);
        acc += __bfloat162float(xb[(size_t)nb * HD + lane]);
    }
    for (int jj = s + 64; jj < e; jj++) {
        acc += __bfloat162float(xb[(size_t)csr[jj] * HD + lane]);
    }
    h[(size_t)row * HD + lane] = acc;
}

// ---------------------------------------------------------------------------
// Layer-1 aggregation with fused BatchNorm+ReLU of the previous layer.
// ---------------------------------------------------------------------------
__global__ __launch_bounds__(256)
void aggn_kernel(const float* __restrict__ hraw, const __hip_bfloat16* __restrict__ xbr,
                 const int* __restrict__ row_ptr, const int* __restrict__ csr,
                 const float* __restrict__ stats_prev, const float* __restrict__ g0,
                 const float* __restrict__ be0,
                 float* __restrict__ h, float* __restrict__ stats_next) {
    if (blockIdx.x == 0 && threadIdx.x < 128) stats_next[threadIdx.x] = 0.f;
    int row = blockIdx.x * 4 + (threadIdx.x >> 6);
    int lane = threadIdx.x & 63;
    const float inv = 1.f / (float)NN;
    float mu = stats_prev[lane] * inv;
    float var = stats_prev[64 + lane] * inv - mu * mu;
    float sc = g0[lane] * rsqrtf(var + BN_EPS);
    float off = be0[lane] - mu * sc;
    int s = row_ptr[row], e = row_ptr[row + 1];
    int cnt = e - s;
    int ids = (lane < cnt) ? csr[s + lane] : 0;
    float acc = fmaxf(fmaf(hraw[(size_t)row * HD + lane], sc, off), 0.f);
    int m = min(cnt, 64);
    int j = 0;
    float a0 = 0.f, a1 = 0.f, a2 = 0.f, a3 = 0.f;
    float a4 = 0.f, a5 = 0.f, a6 = 0.f, a7 = 0.f;
    for (; j + 8 <= m; j += 8) {
        int nb0 = __shfl(ids, j);
        int nb1 = __shfl(ids, j + 1);
        int nb2 = __shfl(ids, j + 2);
        int nb3 = __shfl(ids, j + 3);
        int nb4 = __shfl(ids, j + 4);
        int nb5 = __shfl(ids, j + 5);
        int nb6 = __shfl(ids, j + 6);
        int nb7 = __shfl(ids, j + 7);
        float v0 = __bfloat162float(xbr[(size_t)nb0 * HD + lane]);
        float v1 = __bfloat162float(xbr[(size_t)nb1 * HD + lane]);
        float v2 = __bfloat162float(xbr[(size_t)nb2 * HD + lane]);
        float v3 = __bfloat162float(xbr[(size_t)nb3 * HD + lane]);
        float v4 = __bfloat162float(xbr[(size_t)nb4 * HD + lane]);
        float v5 = __bfloat162float(xbr[(size_t)nb5 * HD + lane]);
        float v6 = __bfloat162float(xbr[(size_t)nb6 * HD + lane]);
        float v7 = __bfloat162float(xbr[(size_t)nb7 * HD + lane]);
        a0 += fmaxf(fmaf(v0, sc, off), 0.f);
        a1 += fmaxf(fmaf(v1, sc, off), 0.f);
        a2 += fmaxf(fmaf(v2, sc, off), 0.f);
        a3 += fmaxf(fmaf(v3, sc, off), 0.f);
        a4 += fmaxf(fmaf(v4, sc, off), 0.f);
        a5 += fmaxf(fmaf(v5, sc, off), 0.f);
        a6 += fmaxf(fmaf(v6, sc, off), 0.f);
        a7 += fmaxf(fmaf(v7, sc, off), 0.f);
    }
    acc += ((a0 + a1) + (a2 + a3)) + ((a4 + a5) + (a6 + a7));
    for (; j < m; j++) {
        int nb = __shfl(ids, j);
        float v = __bfloat162float(xbr[(size_t)nb * HD + lane]);
        acc += fmaxf(fmaf(v, sc, off), 0.f);
    }
    for (int jj = s + 64; jj < e; jj++) {
        float v = __bfloat162float(xbr[(size_t)csr[jj] * HD + lane]);
        acc += fmaxf(fmaf(v, sc, off), 0.f);
    }
    h[(size_t)row * HD + lane] = acc;
}

// ---------------------------------------------------------------------------
// Fused MLP + BN-stats epilogue. Optional bf16 raw dual-write.
// Block 0 zeroes psums.
// ---------------------------------------------------------------------------
__global__ __launch_bounds__(256)
void mlp_kernel(const float* __restrict__ hin, float* __restrict__ hout,
                const float* __restrict__ W1, const float* __restrict__ b1,
                const float* __restrict__ W2, const float* __restrict__ b2,
                float* __restrict__ stats, float* __restrict__ psums,
                __hip_bfloat16* __restrict__ xbr) {
    __shared__ float sh[128 * 65];
    __shared__ float sW[64 * 64];
    __shared__ float sb[64];
    __shared__ float red[2][4][64];
    int tid = threadIdx.x;
    int base = blockIdx.x * 128;

    if (blockIdx.x == 0) {
        float4 z = make_float4(0.f, 0.f, 0.f, 0.f);
        *(float4*)(psums + tid * 4) = z;
    }
    for (int i = tid; i < 4096; i += 256) sW[i] = W1[i];
    if (tid < 64) sb[tid] = b1[tid];
#pragma unroll
    for (int i = 0; i < 8; i++) {
        int i4 = tid + 256 * i;
        int row = i4 >> 4, col = (i4 & 15) * 4;
        int grow = base + row;
        float4 v = (grow < NN) ? *(const float4*)(hin + (size_t)grow * HD + col)
                               : make_float4(0.f, 0.f, 0.f, 0.f);
        float* d = sh + row * 65 + col;
        d[0] = v.x; d[1] = v.y; d[2] = v.z; d[3] = v.w;
    }
    __syncthreads();

    int wv = tid >> 6;
    int lane = tid & 63;

    float acc0[16], acc1[16];
    // ---- GEMM1 ----
#pragma unroll
    for (int j = 0; j < 16; j++) { acc0[j] = sb[wv * 16 + j]; acc1[j] = acc0[j]; }
    for (int k = 0; k < 64; k++) {
        float a0 = sh[lane * 65 + k];
        float a1 = sh[(64 + lane) * 65 + k];
        const float4* wr = (const float4*)(sW + k * 64 + wv * 16);
#pragma unroll
        for (int q = 0; q < 4; q++) {
            float4 w = wr[q];
            acc0[4 * q + 0] = fmaf(a0, w.x, acc0[4 * q + 0]);
            acc0[4 * q + 1] = fmaf(a0, w.y, acc0[4 * q + 1]);
            acc0[4 * q + 2] = fmaf(a0, w.z, acc0[4 * q + 2]);
            acc0[4 * q + 3] = fmaf(a0, w.w, acc0[4 * q + 3]);
            acc1[4 * q + 0] = fmaf(a1, w.x, acc1[4 * q + 0]);
            acc1[4 * q + 1] = fmaf(a1, w.y, acc1[4 * q + 1]);
            acc1[4 * q + 2] = fmaf(a1, w.z, acc1[4 * q + 2]);
            acc1[4 * q + 3] = fmaf(a1, w.w, acc1[4 * q + 3]);
        }
    }
    __syncthreads();

    // t = ReLU(acc) overwrites sh; restage W2/b2
#pragma unroll
    for (int j = 0; j < 16; j++) {
        sh[lane * 65 + wv * 16 + j] = fmaxf(acc0[j], 0.f);
        sh[(64 + lane) * 65 + wv * 16 + j] = fmaxf(acc1[j], 0.f);
    }
    for (int i = tid; i < 4096; i += 256) sW[i] = W2[i];
    if (tid < 64) sb[tid] = b2[tid];
    __syncthreads();

    // ---- GEMM2 ----
#pragma unroll
    for (int j = 0; j < 16; j++) { acc0[j] = sb[wv * 16 + j]; acc1[j] = acc0[j]; }
    for (int k = 0; k < 64; k++) {
        float a0 = sh[lane * 65 + k];
        float a1 = sh[(64 + lane) * 65 + k];
        const float4* wr = (const float4*)(sW + k * 64 + wv * 16);
#pragma unroll
        for (int q = 0; q < 4; q++) {
            float4 w = wr[q];
            acc0[4 * q + 0] = fmaf(a0, w.x, acc0[4 * q + 0]);
            acc0[4 * q + 1] = fmaf(a0, w.y, acc0[4 * q + 1]);
            acc0[4 * q + 2] = fmaf(a0, w.z, acc0[4 * q + 2]);
            acc0[4 * q + 3] = fmaf(a0, w.w, acc0[4 * q + 3]);
            acc1[4 * q + 0] = fmaf(a1, w.x, acc1[4 * q + 0]);
            acc1[4 * q + 1] = fmaf(a1, w.y, acc1[4 * q + 1]);
            acc1[4 * q + 2] = fmaf(a1, w.z, acc1[4 * q + 2]);
            acc1[4 * q + 3] = fmaf(a1, w.w, acc1[4 * q + 3]);
        }
    }
    __syncthreads();
#pragma unroll
    for (int j = 0; j < 16; j++) {
        sh[lane * 65 + wv * 16 + j] = acc0[j];
        sh[(64 + lane) * 65 + wv * 16 + j] = acc1[j];
    }
    __syncthreads();

    // coalesced stores: fp32 always; bf16 raw table if requested
#pragma unroll
    for (int i = 0; i < 8; i++) {
        int i4 = tid + 256 * i;
        int row = i4 >> 4, col = (i4 & 15) * 4;
        int grow = base + row;
        if (grow < NN) {
            const float* s = sh + row * 65 + col;
            float4 v = make_float4(s[0], s[1], s[2], s[3]);
            *(float4*)(hout + (size_t)grow * HD + col) = v;
            if (xbr) {
                union { ushort4 u; __hip_bfloat16 b[4]; } p;
                p.b[0] = __float2bfloat16(v.x);
                p.b[1] = __float2bfloat16(v.y);
                p.b[2] = __float2bfloat16(v.z);
                p.b[3] = __float2bfloat16(v.w);
                *(ushort4*)((unsigned short*)xbr + (size_t)grow * HD + col) = p.u;
            }
        }
    }

    // ---- fused BN-stats partials ----
    {
        int col = tid & 63;
        int r0 = (tid >> 6) * 32;
        float s = 0.f, ss = 0.f;
#pragma unroll
        for (int r = 0; r < 32; r++) {
            float v = (base + r0 + r < NN) ? sh[(r0 + r) * 65 + col] : 0.f;
            s += v;
            ss += v * v;
        }
        red[0][tid >> 6][col] = s;
        red[1][tid >> 6][col] = ss;
        __syncthreads();
        if (tid < 64) {
            float S = red[0][0][col] + red[0][1][col] + red[0][2][col] + red[0][3][col];
            atomicAdd(stats + col, S);
        } else if (tid < 128) {
            float SS = red[1][0][col] + red[1][1][col] + red[1][2][col] + red[1][3][col];
            atomicAdd(stats + 64 + col, SS);
        }
    }
}

// ---------------------------------------------------------------------------
// Final BatchNorm + affine + ReLU, in-place on out, with fused mean-pool
// partials: block covers 16 consecutive rows (<=2 graphs at ~3125 rows/graph);
// LDS-reduce per-graph column sums, then 128 fire-and-forget atomics to psums.
// ---------------------------------------------------------------------------
__global__ __launch_bounds__(256)
void norm_kernel(float* h, const float* __restrict__ stats,
                 const float* __restrict__ g, const float* __restrict__ be,
                 const int* __restrict__ batch, float* __restrict__ psums) {
    __shared__ float sg[2][64];
    if (threadIdx.x < 128) sg[threadIdx.x >> 6][threadIdx.x & 63] = 0.f;
    __syncthreads();
    size_t i4 = (size_t)blockIdx.x * 256 + threadIdx.x;
    int row = (int)(i4 >> 4);            // 16 threads (4 cols each) per row
    int base_row = blockIdx.x * 16;
    int g0 = batch[base_row];
    size_t off = i4 * 4;
    int col = (int)(off & 63);
    float4 v = *(const float4*)(h + off);
    float4 sm = *(const float4*)(stats + col);
    float4 sq = *(const float4*)(stats + 64 + col);
    float4 gg = *(const float4*)(g + col);
    float4 bb = *(const float4*)(be + col);
    const float inv = 1.f / (float)NN;
    float4 o;
    {
        float mu = sm.x * inv, var = sq.x * inv - mu * mu;
        float sc = gg.x * rsqrtf(var + BN_EPS);
        o.x = fmaxf((v.x - mu) * sc + bb.x, 0.f);
    }
    {
        float mu = sm.y * inv, var = sq.y * inv - mu * mu;
        float sc = gg.y * rsqrtf(var + BN_EPS);
        o.y = fmaxf((v.y - mu) * sc + bb.y, 0.f);
    }
    {
        float mu = sm.z * inv, var = sq.z * inv - mu * mu;
        float sc = gg.z * rsqrtf(var + BN_EPS);
        o.z = fmaxf((v.z - mu) * sc + bb.z, 0.f);
    }
    {
        float mu = sm.w * inv, var = sq.w * inv - mu * mu;
        float sc = gg.w * rsqrtf(var + BN_EPS);
        o.w = fmaxf((v.w - mu) * sc + bb.w, 0.f);
    }
    *(float4*)(h + off) = o;

    // pool partials
    int dg = batch[row] - g0;
    if (dg <= 1) {
        atomicAdd(&sg[dg][col + 0], o.x);
        atomicAdd(&sg[dg][col + 1], o.y);
        atomicAdd(&sg[dg][col + 2], o.z);
        atomicAdd(&sg[dg][col + 3], o.w);
    } else {  // >2 graphs in one 16-row window (never at ~3125 rows/graph)
        int gid = g0 + dg;
        atomicAdd(&psums[gid * HD + col + 0], o.x);
        atomicAdd(&psums[gid * HD + col + 1], o.y);
        atomicAdd(&psums[gid * HD + col + 2], o.z);
        atomicAdd(&psums[gid * HD + col + 3], o.w);
    }
    __syncthreads();
    if (threadIdx.x < 128) {
        int d = threadIdx.x >> 6;
        int c = threadIdx.x & 63;
        float s = sg[d][c];
        if (g0 + d < NG && s != 0.f) atomicAdd(&psums[(g0 + d) * HD + c], s);
    }
}

// ---------------------------------------------------------------------------
// Pool finalize: divide psums by graph sizes (batch sorted -> binary search).
// ---------------------------------------------------------------------------
__device__ __forceinline__ int lower_bound_batch(const int* __restrict__ b, int val) {
    int lo = 0, hi = NN;
    while (lo < hi) {
        int mid = (lo + hi) >> 1;
        if (b[mid] < val) lo = mid + 1;
        else hi = mid;
    }
    return lo;
}

__global__ __launch_bounds__(1024)
void pool_finalize_kernel(const float* __restrict__ sums, const int* __restrict__ batch,
                          float* __restrict__ out) {
    int g = threadIdx.x >> 6;
    int col = threadIdx.x & 63;
    int s = lower_bound_batch(batch, g);
    int e = lower_bound_batch(batch, g + 1);
    float cnt = (float)(e - s);
    out[g * HD + col] = sums[g * HD + col] / fmaxf(cnt, 1.f);
}

extern "C" void kernel_launch(void* const* d_in, const int* in_sizes, int n_in,
                              void* d_out, int out_size, void* d_ws, size_t ws_size,
                              hipStream_t stream) {
    const float* x = (const float*)d_in[0];
    const int* ei = (const int*)d_in[1];
    const int* batch = (const int*)d_in[2];
    const float* W1_0 = (const float*)d_in[3];
    const float* b1_0 = (const float*)d_in[4];
    const float* W2_0 = (const float*)d_in[5];
    const float* b2_0 = (const float*)d_in[6];
    const float* g_0 = (const float*)d_in[7];
    const float* be_0 = (const float*)d_in[8];
    const float* W1_1 = (const float*)d_in[9];
    const float* b1_1 = (const float*)d_in[10];
    const float* W2_1 = (const float*)d_in[11];
    const float* b2_1 = (const float*)d_in[12];
    const float* g_1 = (const float*)d_in[13];
    const float* be_1 = (const float*)d_in[14];

    float* out = (float*)d_out;  // raw L0 h2 -> raw L1 h2 -> final normalized

    // workspace layout (~30 MB)
    float* buf_h = (float*)d_ws;                       // NN*HD f32
    float* stats0 = buf_h + (size_t)NN * HD;           // 128 f32
    float* stats1 = stats0 + 128;                      // 128 f32
    float* psums = stats1 + 128;                       // 1024 f32
    int* row_ptr = (int*)(psums + 1024);               // NN+2
    int* cnt = row_ptr + (NN + 2);                     // NN
    int* partials = cnt + NN;                          // 256
    int* gcur = partials + 256;                        // 64
    int* csr = gcur + 64;                              // NE
    __hip_bfloat16* xb = (__hip_bfloat16*)(csr + NE);  // NN*HD bf16
    int2* part = (int2*)(xb + (size_t)NN * HD);        // NE int2

    dim3 b256(256);
    int mlp_grid = (NN + 127) / 128;              // 391
    int norm_grid = (NN * HD / 4 + 255) / 256;    // 3125
    int cnt_grid = (NE / 4 + 255) / 256;          // 782
    int agg_grid = NN / 4;                        // 12500

    // ---- CSR build ----
    x2bf_kernel<<<norm_grid, b256, 0, stream>>>(x, xb, cnt);
    count_kernel<<<cnt_grid, b256, 0, stream>>>(ei, cnt);
    scan1_kernel<<<SCAN_BLOCKS, b256, 0, stream>>>(cnt, row_ptr, partials);
    scan3_kernel<<<SCAN_BLOCKS, b256, 0, stream>>>(row_ptr, partials, gcur);
    bin1_kernel<<<BIN1_BLOCKS, b256, 0, stream>>>(ei, gcur, part);
    bin2_kernel<<<NBUCK, b256, 0, stream>>>(part, row_ptr, csr);

    // ---- layer 0 ----
    agg_kernel<<<agg_grid, b256, 0, stream>>>(x, xb, row_ptr, csr, buf_h, stats0);
    mlp_kernel<<<mlp_grid, b256, 0, stream>>>(buf_h, out, W1_0, b1_0, W2_0, b2_0,
                                              stats0, psums, xb);

    // ---- layer 1 (agg applies layer-0 BN+ReLU on the fly) ----
    aggn_kernel<<<agg_grid, b256, 0, stream>>>(out, xb, row_ptr, csr,
                                               stats0, g_0, be_0, buf_h, stats1);
    mlp_kernel<<<mlp_grid, b256, 0, stream>>>(buf_h, out, W1_1, b1_1, W2_1, b2_1,
                                              stats1, psums, (__hip_bfloat16*)nullptr);

    // ---- final norm + fused pool partials, then tiny finalize ----
    norm_kernel<<<norm_grid, b256, 0, stream>>>(out, stats1, g_1, be_1, batch, psums);
    pool_finalize_kernel<<<1, dim3(1024), 0, stream>>>(psums, batch, out + (size_t)NN * HD);
}